// Round 6
// baseline (533.535 us; speedup 1.0000x reference)
//
#include <hip/hip_runtime.h>

// LSTM: B=4096, T=2048, I=4, H=3, gates i,f,g,o (W rows r = g*3 + u)
// R9: two-stream interleave. R8 lesson: chain stall (~220cy) is trans-
//     dominated (4 serial exp2/rcp @ ~35-40cy dep latency); VALU/DPP stage
//     shaving returns ~0. So HIDE the stall: 8 sequences/wave as two
//     independent streams A,B (16 lanes/seq layout unchanged, duplicated
//     state). The in-wave scheduler fills A's trans latency with B's issue:
//     round-wall ~max(chain 220, 2x issue 130) covering TWO steps.
//     Grid 512 blocks; weights shared across streams (lane-functions only).
//     NO inline asm (asm blocks are atomic to the scheduler -- would block
//     cross-stream interleave; builtins let hazard slots hold B-work).
// R6 step body per stream (best verified): tree h-dot, o-fold, raw stores,
//     len-based tail zero.

#define BB 4096
#define TT 2048
#define L2E 1.4426950408889634f

template<int CTRL>
__device__ __forceinline__ float dppf(float v) {
    return __int_as_float(
        __builtin_amdgcn_update_dpp(0, __float_as_int(v), CTRL, 0xF, 0xF, true));
}

__global__ __launch_bounds__(64, 1) void lstm_seq(
    const float* __restrict__ x, const float* __restrict__ Wih,
    const float* __restrict__ Whh, const float* __restrict__ bih,
    const float* __restrict__ bhh, const int* __restrict__ len,
    float* __restrict__ out)
{
    const int lane  = threadIdx.x & 63;
    const int s     = lane & 3;          // gate: 0=i,1=f,2=g,3=o
    const int q     = (lane >> 2) & 3;   // quad = unit (3 = dup of unit 2)
    const int row16 = lane >> 4;         // sequence-slot within wave
    const int bA    = blockIdx.x * 8 + row16;      // stream A row
    const int bB    = bA + 4;                      // stream B row
    const int u     = (q < 3) ? q : 2;
    const int wrow  = s * 3 + u;

    // r = rcp(1+exp2(a)), a = pre*scale:
    //   sigmoid (s!=2): scale=-log2e,  act = r
    //   tanh    (s==2): scale=+2log2e, act = 2L2E - 4L2E*r  (pre-scaled g)
    // Cell carried as cc = 2*log2e*c; tanh(c) = 1 - 2*rcp(1+exp2(cc)).
    const float scale = (s == 2) ? (2.f * L2E) : (-L2E);
    const float Aa = (s == 2) ? (2.f * L2E) : 0.f;
    const float Bb = (s == 2) ? (-4.f * L2E) : 1.f;

    const float xw0 = Wih[wrow * 4 + 0] * scale;
    const float xw1 = Wih[wrow * 4 + 1] * scale;
    const float xw2 = Wih[wrow * 4 + 2] * scale;
    const float xw3 = Wih[wrow * 4 + 3] * scale;
    const float bias = (bih[wrow] + bhh[wrow]) * scale;

    // h slot j arrives via row_ror:(4j): source quad (q - j) & 3.
    // Zero weight for the dup-quad source (keeps dup bit-synced to unit 2).
    float wh[4];
    #pragma unroll
    for (int j = 0; j < 4; ++j) {
        const int srcq = (q - j) & 3;
        wh[j] = (srcq == 3) ? 0.f : Whh[wrow * 3 + srcq] * scale;
    }

    const int lenA = len[bA];
    const int lenB = len[bB];
    int wmax = max(lenA, lenB);
    #pragma unroll
    for (int off = 1; off < 64; off <<= 1)
        wmax = max(wmax, __shfl_xor(wmax, off));
    const int Tloop = (wmax + 7) & ~7;

    float myhA = 0.f, ccA = 0.f, myhB = 0.f, ccB = 0.f;
    const float4* __restrict__ xrowA = ((const float4*)x) + (size_t)bA * TT;
    const float4* __restrict__ xrowB = ((const float4*)x) + (size_t)bB * TT;
    float* __restrict__ orowA = out + (size_t)bA * (TT * 3);
    float* __restrict__ orowB = out + (size_t)bB * (TT * 3);
    const bool writer = (s == 0) && (q < 3);

    float4 bufA[8], bufB[8];
    float xaccA[8], xaccB[8];
    #pragma unroll
    for (int uu = 0; uu < 8; ++uu) { bufA[uu] = xrowA[uu]; bufB[uu] = xrowB[uu]; }

    for (int tb = 0; tb < Tloop; tb += 8) {
        #pragma unroll
        for (int uu = 0; uu < 8; ++uu) {
            const float4 xa = bufA[uu];
            const float4 xb = bufB[uu];
            xaccA[uu] = fmaf(xw3, xa.w, fmaf(xw2, xa.z,
                        fmaf(xw1, xa.y, fmaf(xw0, xa.x, bias))));
            xaccB[uu] = fmaf(xw3, xb.w, fmaf(xw2, xb.z,
                        fmaf(xw1, xb.y, fmaf(xw0, xb.x, bias))));
        }
        #pragma unroll
        for (int uu = 0; uu < 8; ++uu) {
            const int tn = tb + 8 + uu;
            const int tc = tn < TT ? tn : 0;
            bufA[uu] = xrowA[tc];
            bufB[uu] = xrowB[tc];
        }
        #pragma unroll
        for (int uu = 0; uu < 8; ++uu) {
            const int t = tb + uu;
            // --- interleaved A/B step (independent chains; scheduler fills
            //     each stream's trans/DPP latency with the other's issue) ---
            const float h1A = dppf<0x124>(myhA);   // row_ror:4
            const float h1B = dppf<0x124>(myhB);
            const float h2A = dppf<0x128>(myhA);   // row_ror:8
            const float h2B = dppf<0x128>(myhB);
            const float h3A = dppf<0x12C>(myhA);   // row_ror:12
            const float h3B = dppf<0x12C>(myhB);
            const float p0A = fmaf(wh[0], myhA, xaccA[uu]);
            const float p0B = fmaf(wh[0], myhB, xaccB[uu]);
            const float m3A = wh[3] * h3A;
            const float m3B = wh[3] * h3B;
            const float p1A = fmaf(wh[1], h1A, p0A);
            const float p1B = fmaf(wh[1], h1B, p0B);
            const float p2A = fmaf(wh[2], h2A, m3A);
            const float p2B = fmaf(wh[2], h2B, m3B);
            const float aA  = p1A + p2A;
            const float aB  = p1B + p2B;
            const float rA = __builtin_amdgcn_rcpf(1.f + __builtin_amdgcn_exp2f(aA));
            const float rB = __builtin_amdgcn_rcpf(1.f + __builtin_amdgcn_exp2f(aB));
            const float actA = fmaf(Bb, rA, Aa);
            const float actB = fmaf(Bb, rB, Aa);
            const float giA = dppf<0x00>(actA);
            const float giB = dppf<0x00>(actB);
            const float gfA = dppf<0x55>(actA);
            const float gfB = dppf<0x55>(actB);
            const float ggA = dppf<0xAA>(actA);
            const float ggB = dppf<0xAA>(actB);
            const float goA = dppf<0xFF>(actA);
            const float goB = dppf<0xFF>(actB);
            ccA = fmaf(gfA, ccA, giA * ggA);      // cc = 2L2E * c
            ccB = fmaf(gfB, ccB, giB * ggB);
            const float n2goA = -2.f * goA;
            const float n2goB = -2.f * goB;
            const float r2A = __builtin_amdgcn_rcpf(1.f + __builtin_amdgcn_exp2f(ccA));
            const float r2B = __builtin_amdgcn_rcpf(1.f + __builtin_amdgcn_exp2f(ccB));
            myhA = fmaf(n2goA, r2A, goA);          // o * tanh(c)
            myhB = fmaf(n2goB, r2B, goB);
            if (writer) {
                orowA[t * 3 + q] = myhA;           // raw; tail zeroes t >= len
                orowB[t * 3 + q] = myhB;
            }
        }
    }

    // Order main-loop stores before tail overwrites (same addresses).
    asm volatile("s_waitcnt vmcnt(0)" ::: "memory");

    // Zero t in [len[row], TT) for this wave's 8 rows.
    #pragma unroll
    for (int rr = 0; rr < 8; ++rr) {
        const int bb = blockIdx.x * 8 + rr;
        const int L  = len[bb];
        float* __restrict__ ob = out + (size_t)bb * (TT * 3);
        const int s0 = L * 3;                 // first float to zero
        const int a4 = (s0 + 3) & ~3;         // align up to float4
        if (lane < a4 - s0) ob[s0 + lane] = 0.f;
        float4* __restrict__ o4 = (float4*)ob;
        for (int idx = a4 / 4 + lane; idx < TT * 3 / 4; idx += 64)
            o4[idx] = make_float4(0.f, 0.f, 0.f, 0.f);
    }
}

extern "C" void kernel_launch(void* const* d_in, const int* in_sizes, int n_in,
                              void* d_out, int out_size, void* d_ws, size_t ws_size,
                              hipStream_t stream) {
    const float* x    = (const float*)d_in[0];
    const float* Wih  = (const float*)d_in[1];
    const float* Whh  = (const float*)d_in[2];
    const float* bih  = (const float*)d_in[3];
    const float* bhh  = (const float*)d_in[4];
    const int*   lenp = (const int*)d_in[5];
    float* out = (float*)d_out;

    lstm_seq<<<BB / 8, 64, 0, stream>>>(x, Wih, Whh, bih, bhh, lenp, out);
}

// Round 7
// 406.897 us; speedup vs baseline: 1.3112x; 1.3112x over previous
//
#include <hip/hip_runtime.h>

// LSTM: B=4096, T=2048, I=4, H=3, gates i,f,g,o (W rows r = g*3 + u)
// R10: R6 (best, 243us) + payload-in-trans-shadow. R9 proved wall = 2048 x
//      single-chain step latency (TLP can't help; interleave absorbed issue
//      but doubled round time). Untested lever: PLACEMENT of the ~10 off-chain
//      instrs/step. Put each trans pair in asm with the payload between
//      exp2 and its dependent add -- in-order issue proceeds during exp2
//      latency; only the add stalls:
//        block A: exp2(a) | next-x-proj 4 FMA | 1+e | rcp
//        block B: exp2(cc)| xn=t1+t2, -2*go   | 1+e2| rcp
//      Same instr count as R6, purely relocated; xacc batch loop removed
//      (per-step in shadow), loads per-step.
// R9 lesson: wall = chain latency x T, period. R8: fused-DPP dep ~= pair
//      (no stage gain). R7: added instrs cost ~2cy each. R6 body kept.

#define BB 4096
#define TT 2048
#define L2E 1.4426950408889634f

template<int CTRL>
__device__ __forceinline__ float dppf(float v) {
    return __int_as_float(
        __builtin_amdgcn_update_dpp(0, __float_as_int(v), CTRL, 0xF, 0xF, true));
}

__global__ __launch_bounds__(64, 1) void lstm_seq(
    const float* __restrict__ x, const float* __restrict__ Wih,
    const float* __restrict__ Whh, const float* __restrict__ bih,
    const float* __restrict__ bhh, const int* __restrict__ len,
    float* __restrict__ out)
{
    const int lane  = threadIdx.x & 63;
    const int s     = lane & 3;          // gate: 0=i,1=f,2=g,3=o
    const int q     = (lane >> 2) & 3;   // quad = unit (3 = dup of unit 2)
    const int row16 = lane >> 4;         // sequence within wave (4 per wave)
    const int b     = blockIdx.x * 4 + row16;
    const int u     = (q < 3) ? q : 2;
    const int wrow  = s * 3 + u;

    // r = rcp(1+exp2(a)), a = pre*scale:
    //   sigmoid (s!=2): scale=-log2e,  act = r
    //   tanh    (s==2): scale=+2log2e, act = 2L2E - 4L2E*r  (pre-scaled g)
    // Cell carried as cc = 2*log2e*c; tanh(c) = 1 - 2*rcp(1+exp2(cc)).
    const float scale = (s == 2) ? (2.f * L2E) : (-L2E);
    const float Aa = (s == 2) ? (2.f * L2E) : 0.f;
    const float Bb = (s == 2) ? (-4.f * L2E) : 1.f;

    const float xw0 = Wih[wrow * 4 + 0] * scale;
    const float xw1 = Wih[wrow * 4 + 1] * scale;
    const float xw2 = Wih[wrow * 4 + 2] * scale;
    const float xw3 = Wih[wrow * 4 + 3] * scale;
    const float bias = (bih[wrow] + bhh[wrow]) * scale;

    // h slot j arrives via row_ror:(4j): source quad (q - j) & 3.
    // Zero weight for the dup-quad source (keeps dup bit-synced to unit 2).
    float wh[4];
    #pragma unroll
    for (int j = 0; j < 4; ++j) {
        const int srcq = (q - j) & 3;
        wh[j] = (srcq == 3) ? 0.f : Whh[wrow * 3 + srcq] * scale;
    }

    const int mylen = len[b];
    int wmax = mylen;
    #pragma unroll
    for (int off = 1; off < 64; off <<= 1)
        wmax = max(wmax, __shfl_xor(wmax, off));
    const int Tloop = (wmax + 7) & ~7;

    float myh = 0.f, cc = 0.f;
    const float4* __restrict__ xrow = ((const float4*)x) + (size_t)b * TT;
    float* __restrict__ orow = out + (size_t)b * (TT * 3);
    const bool writer = (s == 0) && (q < 3);

    float4 buf[8];
    #pragma unroll
    for (int uu = 0; uu < 8; ++uu) buf[uu] = xrow[uu];

    // Prologue: xacc for t=0.
    float xacc;
    {
        const float4 b0 = buf[0];
        const float t1p = fmaf(xw1, b0.y, fmaf(xw0, b0.x, bias));
        const float t2p = fmaf(xw3, b0.w, xw2 * b0.z);
        xacc = t1p + t2p;
    }

    for (int tb = 0; tb < Tloop; tb += 8) {
        #pragma unroll
        for (int uu = 0; uu < 8; ++uu) {
            const int t = tb + uu;
            // --- on-chain: h gather + dot (R6 form) ---
            const float h1 = dppf<0x124>(myh);   // row_ror:4  -> quad q-1
            const float h2 = dppf<0x128>(myh);   // row_ror:8  -> quad q-2
            const float h3 = dppf<0x12C>(myh);   // row_ror:12 -> quad q-3
            const float p0 = fmaf(wh[0], myh, xacc);
            const float m3 = wh[3] * h3;
            const float p1 = fmaf(wh[1], h1, p0);
            const float p2 = fmaf(wh[2], h2, m3);
            const float a  = p1 + p2;
            // --- asm A: r = rcp(1+exp2(a)); payload = next-step x-proj ---
            // (payload issues in exp2's latency window; only the add stalls)
            const float4 xv = buf[(uu + 1) & 7];
            float r, t1, t2, e, d;
            asm("v_exp_f32 %[e], %[a]\n\t"
                "v_mul_f32 %[t2], %[w2], %[x2]\n\t"
                "v_fma_f32 %[t1], %[w0], %[x0], %[bi]\n\t"
                "v_fmac_f32 %[t2], %[w3], %[x3]\n\t"
                "v_fmac_f32 %[t1], %[w1], %[x1]\n\t"
                "v_add_f32 %[d], 1.0, %[e]\n\t"
                "v_rcp_f32 %[r], %[d]"
                : [r] "=&v"(r), [t1] "=&v"(t1), [t2] "=&v"(t2),
                  [e] "=&v"(e), [d] "=&v"(d)
                : [a] "v"(a), [x0] "v"(xv.x), [x1] "v"(xv.y),
                  [x2] "v"(xv.z), [x3] "v"(xv.w),
                  [w0] "v"(xw0), [w1] "v"(xw1), [w2] "v"(xw2), [w3] "v"(xw3),
                  [bi] "v"(bias));
            // Refill buf[uu] (old value consumed by prev step's payload).
            {
                const int tn = tb + 8 + uu;
                buf[uu] = xrow[tn < TT ? tn : 0];
            }
            const float act = fmaf(Bb, r, Aa);
            const float gi = dppf<0x00>(act);
            const float gf = dppf<0x55>(act);
            const float gg = dppf<0xAA>(act);   // pre-scaled tanh
            const float go = dppf<0xFF>(act);
            cc = fmaf(gf, cc, gi * gg);          // cc = 2L2E * c
            // --- asm B: r2 = rcp(1+exp2(cc)); payload = xn, -2*go ---
            float r2, xn, ng, e2, d2;
            asm("v_exp_f32 %[e2], %[cc]\n\t"
                "v_add_f32 %[xn], %[t1], %[t2]\n\t"
                "v_mul_f32 %[ng], -2.0, %[go]\n\t"
                "v_add_f32 %[d2], 1.0, %[e2]\n\t"
                "v_rcp_f32 %[r2], %[d2]"
                : [r2] "=&v"(r2), [xn] "=&v"(xn), [ng] "=&v"(ng),
                  [e2] "=&v"(e2), [d2] "=&v"(d2)
                : [cc] "v"(cc), [t1] "v"(t1), [t2] "v"(t2), [go] "v"(go));
            myh = fmaf(ng, r2, go);              // o * tanh(c)
            xacc = xn;                           // next step's x-projection
            if (writer) orow[t * 3 + q] = myh;   // raw; tail zeroes t >= len
        }
    }

    // Order main-loop stores before tail overwrites (same addresses).
    asm volatile("s_waitcnt vmcnt(0)" ::: "memory");

    // Zero t in [len[row], TT) for this wave's 4 rows.
    #pragma unroll
    for (int rr = 0; rr < 4; ++rr) {
        const int bb = blockIdx.x * 4 + rr;
        const int L  = len[bb];
        float* __restrict__ ob = out + (size_t)bb * (TT * 3);
        const int s0 = L * 3;                 // first float to zero
        const int a4 = (s0 + 3) & ~3;         // align up to float4
        if (lane < a4 - s0) ob[s0 + lane] = 0.f;
        float4* __restrict__ o4 = (float4*)ob;
        for (int idx = a4 / 4 + lane; idx < TT * 3 / 4; idx += 64)
            o4[idx] = make_float4(0.f, 0.f, 0.f, 0.f);
    }
}

extern "C" void kernel_launch(void* const* d_in, const int* in_sizes, int n_in,
                              void* d_out, int out_size, void* d_ws, size_t ws_size,
                              hipStream_t stream) {
    const float* x    = (const float*)d_in[0];
    const float* Wih  = (const float*)d_in[1];
    const float* Whh  = (const float*)d_in[2];
    const float* bih  = (const float*)d_in[3];
    const float* bhh  = (const float*)d_in[4];
    const int*   lenp = (const int*)d_in[5];
    float* out = (float*)d_out;

    lstm_seq<<<BB / 4, 64, 0, stream>>>(x, Wih, Whh, bih, bhh, lenp, out);
}

// Round 8
// 390.926 us; speedup vs baseline: 1.3648x; 1.0409x over previous
//
#include <hip/hip_runtime.h>

// LSTM: B=4096, T=2048, I=4, H=3, gates i,f,g,o (W rows r = g*3 + u)
// R11: R6 chain (best, 243us) + store/issue de-clutter. Ledger: stage-shave
//      flat (R8), payload placement flat (R10: compiler already fills stall
//      windows), TLP impossible (R9), BUT store-machinery removal paid 28cy
//      (R6). Exec-mask dances + bounds clamps don't hide in stall windows
//      (scalar-pipe exec writes serialize; DPPs need full exec restored). So:
//      - msave[8]: ONE if(writer) block per 8 steps (1 exec dance, constant-
//        offset stores) instead of per-step predicated stores.
//      - prefetch peel: uniform scalar guard if(tb+8<TT) replaces 8 per-lane
//        cmp+cndmask clamps (Tloop<TT => tn<=Tloop+7<=2047 in-bounds; only
//        the Tloop==2048 last block skips).
//      Chain, layout, tail untouched from R6.

#define BB 4096
#define TT 2048
#define L2E 1.4426950408889634f

template<int CTRL>
__device__ __forceinline__ float dppf(float v) {
    return __int_as_float(
        __builtin_amdgcn_update_dpp(0, __float_as_int(v), CTRL, 0xF, 0xF, true));
}

__global__ __launch_bounds__(64, 1) void lstm_seq(
    const float* __restrict__ x, const float* __restrict__ Wih,
    const float* __restrict__ Whh, const float* __restrict__ bih,
    const float* __restrict__ bhh, const int* __restrict__ len,
    float* __restrict__ out)
{
    const int lane  = threadIdx.x & 63;
    const int s     = lane & 3;          // gate: 0=i,1=f,2=g,3=o
    const int q     = (lane >> 2) & 3;   // quad = unit (3 = dup of unit 2)
    const int row16 = lane >> 4;         // sequence within wave (4 per wave)
    const int b     = blockIdx.x * 4 + row16;
    const int u     = (q < 3) ? q : 2;
    const int wrow  = s * 3 + u;

    // r = rcp(1+exp2(a)), a = pre*scale:
    //   sigmoid (s!=2): scale=-log2e,  act = r
    //   tanh    (s==2): scale=+2log2e, act = 2L2E - 4L2E*r  (pre-scaled g)
    // Cell carried as cc = 2*log2e*c; tanh(c) = 1 - 2*rcp(1+exp2(cc)).
    const float scale = (s == 2) ? (2.f * L2E) : (-L2E);
    const float Aa = (s == 2) ? (2.f * L2E) : 0.f;
    const float Bb = (s == 2) ? (-4.f * L2E) : 1.f;

    const float xw0 = Wih[wrow * 4 + 0] * scale;
    const float xw1 = Wih[wrow * 4 + 1] * scale;
    const float xw2 = Wih[wrow * 4 + 2] * scale;
    const float xw3 = Wih[wrow * 4 + 3] * scale;
    const float bias = (bih[wrow] + bhh[wrow]) * scale;

    // h slot j arrives via row_ror:(4j): source quad (q - j) & 3.
    // Zero weight for the dup-quad source (keeps dup bit-synced to unit 2).
    float wh[4];
    #pragma unroll
    for (int j = 0; j < 4; ++j) {
        const int srcq = (q - j) & 3;
        wh[j] = (srcq == 3) ? 0.f : Whh[wrow * 3 + srcq] * scale;
    }

    const int mylen = len[b];
    int wmax = mylen;
    #pragma unroll
    for (int off = 1; off < 64; off <<= 1)
        wmax = max(wmax, __shfl_xor(wmax, off));
    const int Tloop = (wmax + 7) & ~7;

    float myh = 0.f, cc = 0.f;
    const float4* __restrict__ xrow = ((const float4*)x) + (size_t)b * TT;
    float* __restrict__ orow = out + (size_t)b * (TT * 3);
    const bool writer = (s == 0) && (q < 3);

    float4 buf[8];
    float xacc[8];
    #pragma unroll
    for (int uu = 0; uu < 8; ++uu) buf[uu] = xrow[uu];

    for (int tb = 0; tb < Tloop; tb += 8) {
        #pragma unroll
        for (int uu = 0; uu < 8; ++uu) {
            const float4 xv = buf[uu];
            xacc[uu] = fmaf(xw3, xv.w, fmaf(xw2, xv.z,
                       fmaf(xw1, xv.y, fmaf(xw0, xv.x, bias))));
        }
        // Prefetch next block, uniform scalar guard (no per-lane clamps).
        // Tloop<TT => tb+8+7 <= Tloop+7 <= 2047 in-bounds; only the
        // Tloop==2048 final block (tb+8==TT) skips.
        if (tb + 8 < TT) {
            #pragma unroll
            for (int uu = 0; uu < 8; ++uu)
                buf[uu] = xrow[tb + 8 + uu];
        }
        float msave[8];
        #pragma unroll
        for (int uu = 0; uu < 8; ++uu) {
            // h gather: VALU-pipe DPP row rotates (row = 16 lanes).
            const float h1 = dppf<0x124>(myh);   // row_ror:4  -> quad q-1
            const float h2 = dppf<0x128>(myh);   // row_ror:8  -> quad q-2
            const float h3 = dppf<0x12C>(myh);   // row_ror:12 -> quad q-3
            // Tree: p0 has no DPP dependence; gathered terms pair up.
            const float p0 = fmaf(wh[0], myh, xacc[uu]);
            const float m3 = wh[3] * h3;
            const float p1 = fmaf(wh[1], h1, p0);
            const float p2 = fmaf(wh[2], h2, m3);
            const float a  = p1 + p2;
            const float r = __builtin_amdgcn_rcpf(1.f + __builtin_amdgcn_exp2f(a));
            const float act = fmaf(Bb, r, Aa);
            const float gi = dppf<0x00>(act);   // lane 0 of quad: gate i
            const float gf = dppf<0x55>(act);   // gate f
            const float gg = dppf<0xAA>(act);   // gate g (pre-scaled tanh)
            const float go = dppf<0xFF>(act);   // gate o
            cc = fmaf(gf, cc, gi * gg);         // cc = 2L2E * c
            const float n2go = -2.f * go;       // forms in exp2(cc) shadow
            const float r2 = __builtin_amdgcn_rcpf(1.f + __builtin_amdgcn_exp2f(cc));
            myh = fmaf(n2go, r2, go);           // o * tanh(c)
            msave[uu] = myh;
        }
        if (writer) {
            float* __restrict__ op = orow + tb * 3 + q;
            #pragma unroll
            for (int uu = 0; uu < 8; ++uu)
                op[uu * 3] = msave[uu];         // raw; tail zeroes t >= len
        }
    }

    // Order main-loop stores before tail overwrites (same addresses).
    asm volatile("s_waitcnt vmcnt(0)" ::: "memory");

    // Zero t in [len[row], TT) for this wave's 4 rows.
    #pragma unroll
    for (int rr = 0; rr < 4; ++rr) {
        const int bb = blockIdx.x * 4 + rr;
        const int L  = len[bb];
        float* __restrict__ ob = out + (size_t)bb * (TT * 3);
        const int s0 = L * 3;                 // first float to zero
        const int a4 = (s0 + 3) & ~3;         // align up to float4
        if (lane < a4 - s0) ob[s0 + lane] = 0.f;
        float4* __restrict__ o4 = (float4*)ob;
        for (int idx = a4 / 4 + lane; idx < TT * 3 / 4; idx += 64)
            o4[idx] = make_float4(0.f, 0.f, 0.f, 0.f);
    }
}

extern "C" void kernel_launch(void* const* d_in, const int* in_sizes, int n_in,
                              void* d_out, int out_size, void* d_ws, size_t ws_size,
                              hipStream_t stream) {
    const float* x    = (const float*)d_in[0];
    const float* Wih  = (const float*)d_in[1];
    const float* Whh  = (const float*)d_in[2];
    const float* bih  = (const float*)d_in[3];
    const float* bhh  = (const float*)d_in[4];
    const int*   lenp = (const int*)d_in[5];
    float* out = (float*)d_out;

    lstm_seq<<<BB / 4, 64, 0, stream>>>(x, Wih, Whh, bih, bhh, lenp, out);
}

// Round 9
// 369.961 us; speedup vs baseline: 1.4421x; 1.0567x over previous
//
#include <hip/hip_runtime.h>

// LSTM: B=4096, T=2048, I=4, H=3, gates i,f,g,o (W rows r = g*3 + u)
// R12: R11 + the last machinery scraps. Ledger: every win (R6,R11) removed
//      exec/store/predicate machinery; every chain restructure (R5,R7-R10)
//      was flat/regressed. Remaining scraps:
//      - ALL-LANE stores: every lane of a quad holds the identical myh of its
//        unit (gates quad-broadcast, cc/r2 quad-uniform; dup quad bit-synced
//        to unit 2), so every lane stores orow[t*3+u] unconditionally --
//        same value to same address is harmless; writer flag + exec dance
//        deleted entirely.
//      - 16-step unroll: halves per-block scalar overhead (back-edge+guard).
//      Chain untouched (provably minimal gate algebra; 4-trans serial cycle
//      irreducible). If <2% gain: step == chain latency, structural floor.

#define BB 4096
#define TT 2048
#define L2E 1.4426950408889634f

template<int CTRL>
__device__ __forceinline__ float dppf(float v) {
    return __int_as_float(
        __builtin_amdgcn_update_dpp(0, __float_as_int(v), CTRL, 0xF, 0xF, true));
}

__global__ __launch_bounds__(64, 1) void lstm_seq(
    const float* __restrict__ x, const float* __restrict__ Wih,
    const float* __restrict__ Whh, const float* __restrict__ bih,
    const float* __restrict__ bhh, const int* __restrict__ len,
    float* __restrict__ out)
{
    const int lane  = threadIdx.x & 63;
    const int s     = lane & 3;          // gate: 0=i,1=f,2=g,3=o
    const int q     = (lane >> 2) & 3;   // quad = unit (3 = dup of unit 2)
    const int row16 = lane >> 4;         // sequence within wave (4 per wave)
    const int b     = blockIdx.x * 4 + row16;
    const int u     = (q < 3) ? q : 2;
    const int wrow  = s * 3 + u;

    // r = rcp(1+exp2(a)), a = pre*scale:
    //   sigmoid (s!=2): scale=-log2e,  act = r
    //   tanh    (s==2): scale=+2log2e, act = 2L2E - 4L2E*r  (pre-scaled g)
    // Cell carried as cc = 2*log2e*c; tanh(c) = 1 - 2*rcp(1+exp2(cc)).
    const float scale = (s == 2) ? (2.f * L2E) : (-L2E);
    const float Aa = (s == 2) ? (2.f * L2E) : 0.f;
    const float Bb = (s == 2) ? (-4.f * L2E) : 1.f;

    const float xw0 = Wih[wrow * 4 + 0] * scale;
    const float xw1 = Wih[wrow * 4 + 1] * scale;
    const float xw2 = Wih[wrow * 4 + 2] * scale;
    const float xw3 = Wih[wrow * 4 + 3] * scale;
    const float bias = (bih[wrow] + bhh[wrow]) * scale;

    // h slot j arrives via row_ror:(4j): source quad (q - j) & 3.
    // Zero weight for the dup-quad source (keeps dup bit-synced to unit 2).
    float wh[4];
    #pragma unroll
    for (int j = 0; j < 4; ++j) {
        const int srcq = (q - j) & 3;
        wh[j] = (srcq == 3) ? 0.f : Whh[wrow * 3 + srcq] * scale;
    }

    const int mylen = len[b];
    int wmax = mylen;
    #pragma unroll
    for (int off = 1; off < 64; off <<= 1)
        wmax = max(wmax, __shfl_xor(wmax, off));
    const int Tloop = (wmax + 15) & ~15;

    float myh = 0.f, cc = 0.f;
    const float4* __restrict__ xrow = ((const float4*)x) + (size_t)b * TT;
    float* __restrict__ orow = out + (size_t)b * (TT * 3);

    float4 buf[16];
    float xacc[16];
    #pragma unroll
    for (int uu = 0; uu < 16; ++uu) buf[uu] = xrow[uu];

    for (int tb = 0; tb < Tloop; tb += 16) {
        #pragma unroll
        for (int uu = 0; uu < 16; ++uu) {
            const float4 xv = buf[uu];
            xacc[uu] = fmaf(xw3, xv.w, fmaf(xw2, xv.z,
                       fmaf(xw1, xv.y, fmaf(xw0, xv.x, bias))));
        }
        // Prefetch next block, uniform scalar guard (no per-lane clamps).
        // Tloop<TT => tb+16+15 <= Tloop+15 <= 2047 in-bounds; only the
        // Tloop==2048 final block (tb+16==TT) skips.
        if (tb + 16 < TT) {
            #pragma unroll
            for (int uu = 0; uu < 16; ++uu)
                buf[uu] = xrow[tb + 16 + uu];
        }
        float msave[16];
        #pragma unroll
        for (int uu = 0; uu < 16; ++uu) {
            // h gather: VALU-pipe DPP row rotates (row = 16 lanes).
            const float h1 = dppf<0x124>(myh);   // row_ror:4  -> quad q-1
            const float h2 = dppf<0x128>(myh);   // row_ror:8  -> quad q-2
            const float h3 = dppf<0x12C>(myh);   // row_ror:12 -> quad q-3
            // Tree: p0 has no DPP dependence; gathered terms pair up.
            const float p0 = fmaf(wh[0], myh, xacc[uu]);
            const float m3 = wh[3] * h3;
            const float p1 = fmaf(wh[1], h1, p0);
            const float p2 = fmaf(wh[2], h2, m3);
            const float a  = p1 + p2;
            const float r = __builtin_amdgcn_rcpf(1.f + __builtin_amdgcn_exp2f(a));
            const float act = fmaf(Bb, r, Aa);
            const float gi = dppf<0x00>(act);   // lane 0 of quad: gate i
            const float gf = dppf<0x55>(act);   // gate f
            const float gg = dppf<0xAA>(act);   // gate g (pre-scaled tanh)
            const float go = dppf<0xFF>(act);   // gate o
            cc = fmaf(gf, cc, gi * gg);         // cc = 2L2E * c
            const float n2go = -2.f * go;       // forms in exp2(cc) shadow
            const float r2 = __builtin_amdgcn_rcpf(1.f + __builtin_amdgcn_exp2f(cc));
            myh = fmaf(n2go, r2, go);           // o * tanh(c)
            msave[uu] = myh;
        }
        // All-lane stores: every lane of quad q holds the identical myh of
        // unit u; duplicate same-value same-address stores are harmless.
        {
            float* __restrict__ op = orow + tb * 3 + u;
            #pragma unroll
            for (int uu = 0; uu < 16; ++uu)
                op[uu * 3] = msave[uu];         // raw; tail zeroes t >= len
        }
    }

    // Order main-loop stores before tail overwrites (same addresses).
    asm volatile("s_waitcnt vmcnt(0)" ::: "memory");

    // Zero t in [len[row], TT) for this wave's 4 rows.
    #pragma unroll
    for (int rr = 0; rr < 4; ++rr) {
        const int bb = blockIdx.x * 4 + rr;
        const int L  = len[bb];
        float* __restrict__ ob = out + (size_t)bb * (TT * 3);
        const int s0 = L * 3;                 // first float to zero
        const int a4 = (s0 + 3) & ~3;         // align up to float4
        if (lane < a4 - s0) ob[s0 + lane] = 0.f;
        float4* __restrict__ o4 = (float4*)ob;
        for (int idx = a4 / 4 + lane; idx < TT * 3 / 4; idx += 64)
            o4[idx] = make_float4(0.f, 0.f, 0.f, 0.f);
    }
}

extern "C" void kernel_launch(void* const* d_in, const int* in_sizes, int n_in,
                              void* d_out, int out_size, void* d_ws, size_t ws_size,
                              hipStream_t stream) {
    const float* x    = (const float*)d_in[0];
    const float* Wih  = (const float*)d_in[1];
    const float* Whh  = (const float*)d_in[2];
    const float* bih  = (const float*)d_in[3];
    const float* bhh  = (const float*)d_in[4];
    const int*   lenp = (const int*)d_in[5];
    float* out = (float*)d_out;

    lstm_seq<<<BB / 4, 64, 0, stream>>>(x, Wih, Whh, bih, bhh, lenp, out);
}